// Round 7
// baseline (1741.388 us; speedup 1.0000x reference)
//
#include <hip/hip_runtime.h>
#include <hip/hip_bf16.h>
#include <math.h>

// Qwen3 attention forward. Split-bf16 MFMA GEMMs + split-bf16 MFMA flash attn.
// B=2, S=2048, HID=2560, NH=32, NKV=8, HD=128, GROUPS=4, THETA=1e6, EPS=1e-6
#define B_ 2
#define S_ 2048
#define HID_ 2560
#define NH_ 32
#define NKV_ 8
#define HD_ 128

typedef __attribute__((ext_vector_type(8))) short bf16x8;
typedef __attribute__((ext_vector_type(4))) float f32x4;

union U8 { bf16x8 v; unsigned short u[8]; };

__device__ __forceinline__ unsigned short f2bf(float x) {
    unsigned u = __float_as_uint(x);
    u = u + 0x7FFF + ((u >> 16) & 1);          // round-to-nearest-even
    return (unsigned short)(u >> 16);
}
__device__ __forceinline__ float bf2f(unsigned short h) {
    return __uint_as_float(((unsigned)h) << 16);
}

#define GL16(g, l)                                                             \
    __builtin_amdgcn_global_load_lds(                                          \
        (const __attribute__((address_space(1))) void*)(g),                    \
        (__attribute__((address_space(3))) void*)(l), 16, 0, 0)

// ---------------------------------------------------------------------------
// RoPE cos/sin table [S][64]: fp32 inv_freq (correctly rounded), fp32 product,
// precise fp32 cos/sin — emulates the reference's rounding.
// ---------------------------------------------------------------------------
__global__ void rope_table_kernel(float* __restrict__ cost, float* __restrict__ sint) {
    int t = blockIdx.x;
    int j = threadIdx.x;
    float invf = (float)pow(1.0e6, -(double)j / 64.0);
    float ang  = (float)t * invf;
    cost[t * 64 + j] = cosf(ang);
    sint[t * 64 + j] = sinf(ang);
}

// ---------------------------------------------------------------------------
// fp32 -> (hi,lo) bf16 split, elementwise. n4 = n/4.
// ---------------------------------------------------------------------------
__global__ __launch_bounds__(256) void convert_split(const float* __restrict__ in,
                                                     unsigned short* __restrict__ hi,
                                                     unsigned short* __restrict__ lo,
                                                     int n4) {
    int i = blockIdx.x * 256 + threadIdx.x;
    if (i >= n4) return;
    float4 v = *(const float4*)(in + (size_t)i * 4);
    ushort4 h, l;
    h.x = f2bf(v.x); l.x = f2bf(v.x - bf2f(h.x));
    h.y = f2bf(v.y); l.y = f2bf(v.y - bf2f(h.y));
    h.z = f2bf(v.z); l.z = f2bf(v.z - bf2f(h.z));
    h.w = f2bf(v.w); l.w = f2bf(v.w - bf2f(h.w));
    *(ushort4*)(hi + (size_t)i * 4) = h;
    *(ushort4*)(lo + (size_t)i * 4) = l;
}

// ---------------------------------------------------------------------------
// fp32 [K][N] -> transposed (hi,lo) bf16 [N][K]. K%32==0, N%32==0.
// ---------------------------------------------------------------------------
__global__ __launch_bounds__(256) void convert_T(const float* __restrict__ in,
                                                 unsigned short* __restrict__ hiT,
                                                 unsigned short* __restrict__ loT,
                                                 int K, int N) {
    __shared__ float t[32][33];
    int k0 = blockIdx.y * 32, n0 = blockIdx.x * 32;
    int tr = threadIdx.x >> 5, tc = threadIdx.x & 31;
#pragma unroll
    for (int i = 0; i < 4; ++i)
        t[tr + i * 8][tc] = in[(size_t)(k0 + tr + i * 8) * N + n0 + tc];
    __syncthreads();
#pragma unroll
    for (int i = 0; i < 4; ++i) {
        int n = tr + i * 8, k = tc;
        float x = t[k][n];
        unsigned short h = f2bf(x);
        hiT[(size_t)(n0 + n) * K + k0 + k] = h;
        loT[(size_t)(n0 + n) * K + k0 + k] = f2bf(x - bf2f(h));
    }
}

// ---------------------------------------------------------------------------
// Split-bf16 MFMA GEMM: C[M,N] fp32 = A[M,K] x B[K,N]; A (Ah,Al) row-major,
// B transposed (BhT,BlT) [N][K]. 128x128 tile, BK=32, 4 waves 2x2,
// 3 MFMAs per frag pair. LDS XOR swizzle cb ^= (row&3)<<4 on BOTH global
// source and ds_read (global_load_lds dest linear).
// ---------------------------------------------------------------------------
__global__ __launch_bounds__(256) void gemm_split(const unsigned short* __restrict__ Ah,
                                                  const unsigned short* __restrict__ Al,
                                                  const unsigned short* __restrict__ Bh,
                                                  const unsigned short* __restrict__ Bl,
                                                  float* __restrict__ C,
                                                  int K, int N) {
    __shared__ unsigned short sAh[128 * 32], sAl[128 * 32];
    __shared__ unsigned short sBh[128 * 32], sBl[128 * 32];

    int tid  = threadIdx.x;
    int bn   = blockIdx.x, bm = blockIdx.y;
    int wave = tid >> 6, lane = tid & 63;
    int wr   = wave >> 1, wc = wave & 1;

    int r0  = tid >> 2;
    int cbp = (tid & 3) << 4;
    int e0  = (cbp ^ ((r0 & 3) << 4)) >> 1;

    const unsigned short* gAh = Ah + (size_t)(bm * 128 + r0) * K + e0;
    const unsigned short* gAl = Al + (size_t)(bm * 128 + r0) * K + e0;
    const unsigned short* gBh = Bh + (size_t)(bn * 128 + r0) * K + e0;
    const unsigned short* gBl = Bl + (size_t)(bn * 128 + r0) * K + e0;
    size_t rstep = (size_t)64 * K;

    char* lA_h = (char*)sAh + wave * 1024;
    char* lA_l = (char*)sAl + wave * 1024;
    char* lB_h = (char*)sBh + wave * 1024;
    char* lB_l = (char*)sBl + wave * 1024;

    int l15 = lane & 15, kh = lane >> 4;

    f32x4 acc[4][4];
#pragma unroll
    for (int i = 0; i < 4; ++i)
#pragma unroll
        for (int j = 0; j < 4; ++j) acc[i][j] = (f32x4)0.f;

    for (int k0 = 0; k0 < K; k0 += 32) {
        GL16(gAh + k0,         lA_h);
        GL16(gAh + rstep + k0, lA_h + 4096);
        GL16(gAl + k0,         lA_l);
        GL16(gAl + rstep + k0, lA_l + 4096);
        GL16(gBh + k0,         lB_h);
        GL16(gBh + rstep + k0, lB_h + 4096);
        GL16(gBl + k0,         lB_l);
        GL16(gBl + rstep + k0, lB_l + 4096);
        __syncthreads();

        bf16x8 fah[4], fal[4], fbh[4], fbl[4];
#pragma unroll
        for (int i = 0; i < 4; ++i) {
            int ar   = wr * 64 + i * 16 + l15;
            int arcb = (kh * 16) ^ ((ar & 3) << 4);
            fah[i] = *(const bf16x8*)((const char*)sAh + ar * 64 + arcb);
            fal[i] = *(const bf16x8*)((const char*)sAl + ar * 64 + arcb);
            int br   = wc * 64 + i * 16 + l15;
            int brcb = (kh * 16) ^ ((br & 3) << 4);
            fbh[i] = *(const bf16x8*)((const char*)sBh + br * 64 + brcb);
            fbl[i] = *(const bf16x8*)((const char*)sBl + br * 64 + brcb);
        }
#pragma unroll
        for (int mi = 0; mi < 4; ++mi)
#pragma unroll
            for (int ni = 0; ni < 4; ++ni) {
                acc[mi][ni] = __builtin_amdgcn_mfma_f32_16x16x32_bf16(fah[mi], fbh[ni], acc[mi][ni], 0, 0, 0);
                acc[mi][ni] = __builtin_amdgcn_mfma_f32_16x16x32_bf16(fah[mi], fbl[ni], acc[mi][ni], 0, 0, 0);
                acc[mi][ni] = __builtin_amdgcn_mfma_f32_16x16x32_bf16(fal[mi], fbh[ni], acc[mi][ni], 0, 0, 0);
            }
        __syncthreads();
    }

#pragma unroll
    for (int mi = 0; mi < 4; ++mi) {
        int row0 = bm * 128 + wr * 64 + mi * 16 + (lane >> 4) * 4;
#pragma unroll
        for (int ni = 0; ni < 4; ++ni) {
            int col = bn * 128 + wc * 64 + ni * 16 + (lane & 15);
#pragma unroll
            for (int j = 0; j < 4; ++j)
                C[(size_t)(row0 + j) * N + col] = acc[mi][ni][j];
        }
    }
}

// ---------------------------------------------------------------------------
// Fused per-head RMSNorm + RoPE + transpose, fp32 out (Q path).
// raw: [B*S, rowStride]; outT: [B, H, S, 128]. One wave per (b,s,h) row.
// ---------------------------------------------------------------------------
__global__ __launch_bounds__(256) void rmsnorm_rope_kernel(
        const float* __restrict__ raw, const float* __restrict__ normw,
        const float* __restrict__ cost, const float* __restrict__ sint,
        const int* __restrict__ pos, float* __restrict__ outT,
        int H, int rowStride) {
    int wave = threadIdx.x >> 6;
    int lane = threadIdx.x & 63;
    int row  = blockIdx.x * 4 + wave;
    int h  = row % H;
    int bs = row / H;
    int b  = bs >> 11;
    int s  = bs & (S_ - 1);

    const float* x = raw + (size_t)bs * rowStride + h * HD_;
    float x1 = x[lane];
    float x2 = x[lane + 64];

    float ss = x1 * x1 + x2 * x2;
#pragma unroll
    for (int off = 32; off; off >>= 1) ss += __shfl_xor(ss, off);
    float inv = rsqrtf(ss * (1.0f / 128.0f) + 1e-6f);

    float n1 = x1 * inv * normw[lane];
    float n2 = x2 * inv * normw[lane + 64];

    int p  = pos[bs];
    float c  = cost[p * 64 + lane];
    float sn = sint[p * 64 + lane];
    float o1 = n1 * c - n2 * sn;
    float o2 = n2 * c + n1 * sn;

    float* o = outT + ((size_t)(b * H + h) * S_ + s) * HD_;
    o[lane]      = o1;
    o[lane + 64] = o2;
}

// ---------------------------------------------------------------------------
// K path: RMSNorm + RoPE + transpose + split-bf16.
// raw: [B*S, 2048] (K at head*128); out hi/lo: [B, NKV, S, 128] bf16.
// ---------------------------------------------------------------------------
__global__ __launch_bounds__(256) void rmsnorm_rope_k_split(
        const float* __restrict__ raw, const float* __restrict__ normw,
        const float* __restrict__ cost, const float* __restrict__ sint,
        const int* __restrict__ pos,
        unsigned short* __restrict__ outH, unsigned short* __restrict__ outL) {
    int wave = threadIdx.x >> 6;
    int lane = threadIdx.x & 63;
    int row  = blockIdx.x * 4 + wave;
    int h  = row & 7;                 // NKV=8
    int bs = row >> 3;
    int b  = bs >> 11;
    int s  = bs & (S_ - 1);

    const float* x = raw + (size_t)bs * 2048 + h * HD_;
    float x1 = x[lane];
    float x2 = x[lane + 64];

    float ss = x1 * x1 + x2 * x2;
#pragma unroll
    for (int off = 32; off; off >>= 1) ss += __shfl_xor(ss, off);
    float inv = rsqrtf(ss * (1.0f / 128.0f) + 1e-6f);

    float n1 = x1 * inv * normw[lane];
    float n2 = x2 * inv * normw[lane + 64];

    int p  = pos[bs];
    float c  = cost[p * 64 + lane];
    float sn = sint[p * 64 + lane];
    float o1 = n1 * c - n2 * sn;
    float o2 = n2 * c + n1 * sn;

    size_t base = ((size_t)(b * NKV_ + h) * S_ + s) * HD_;
    unsigned short h1 = f2bf(o1), h2 = f2bf(o2);
    outH[base + lane]      = h1;
    outH[base + lane + 64] = h2;
    outL[base + lane]      = f2bf(o1 - bf2f(h1));
    outL[base + lane + 64] = f2bf(o2 - bf2f(h2));
}

// ---------------------------------------------------------------------------
// V transpose + split: kv fp32 [B*S][2048] (V at 1024 + kvh*128) ->
// vtT hi/lo [B][NKV][128][S] bf16.
// ---------------------------------------------------------------------------
__global__ __launch_bounds__(256) void vsplitT(const float* __restrict__ kv,
                                               unsigned short* __restrict__ vh,
                                               unsigned short* __restrict__ vl) {
    __shared__ float t[32][33];
    int s0 = blockIdx.x * 32;          // 64 tiles
    int d0 = blockIdx.y * 32;          // 4 tiles
    int bi = blockIdx.z;               // b*8 + kvh
    int b  = bi >> 3, kvh = bi & 7;
    int tr = threadIdx.x >> 5, tc = threadIdx.x & 31;
#pragma unroll
    for (int i = 0; i < 4; ++i)
        t[tr + i * 8][tc] = kv[(size_t)(b * S_ + s0 + tr + i * 8) * 2048 + 1024 + kvh * 128 + d0 + tc];
    __syncthreads();
#pragma unroll
    for (int i = 0; i < 4; ++i) {
        int d = tr + i * 8, s = tc;
        float x = t[s][d];
        size_t idx = ((size_t)(bi * 128 + d0 + d)) * S_ + s0 + s;
        unsigned short h = f2bf(x);
        vh[idx] = h;
        vl[idx] = f2bf(x - bf2f(h));
    }
}

// ---------------------------------------------------------------------------
// Causal GQA flash attention, split-bf16 MFMA.
// qt: [B,NH,S,128] f32 (normed+roped); K split: [B,NKV,S,128] bf16 hi/lo;
// V^T split: [B,NKV,128,S] bf16 hi/lo; aout: [B*S][4096] f32.
// Block: 256 thr = 4 waves; QBLK=128 (32 q/wave as 2 m-tiles); KVBLK=64.
// LDS 64KB: Kh[16K] Klo[16K] Vh[16K] Vlo[16K]; P (8KB/wave packed u32)
// overlays Kh/Klo between barriers.
// ---------------------------------------------------------------------------
__global__ __launch_bounds__(256) void attn_mfma(const float* __restrict__ qt,
                                                 const unsigned short* __restrict__ kth,
                                                 const unsigned short* __restrict__ ktl,
                                                 const unsigned short* __restrict__ vth,
                                                 const unsigned short* __restrict__ vtl,
                                                 float* __restrict__ aout) {
    __shared__ char lds[65536];
    char* Kh  = lds;            // [64 keys][256B]  (bf16 hi)
    char* Klo = lds + 16384;
    char* Vh  = lds + 32768;    // [128 d][128B]    (V^T bf16 hi)
    char* Vlo = lds + 49152;

    int tid = threadIdx.x, lane = tid & 63, w = tid >> 6;
    int g = lane >> 4, l15 = lane & 15;
    int qb = blockIdx.x, h = blockIdx.y, b = blockIdx.z;
    int kvh = h >> 2;
    int q0 = qb * 128;
    int wq = q0 + w * 32;
    int wrowmax = wq + 31;

    const float scale = 0.08838834764831845f;   // 1/sqrt(128)

    // ---- Q fragments (hi/lo), held in registers for the whole block ----
    U8 qh[2][4], ql[2][4];
    {
        const float* qbase = qt + ((size_t)(b * NH_ + h) * S_ + wq) * HD_;
#pragma unroll
        for (int mt = 0; mt < 2; ++mt) {
            const float* qr = qbase + (mt * 16 + l15) * HD_;
#pragma unroll
            for (int ks = 0; ks < 4; ++ks) {
                float4 a0 = *(const float4*)(qr + ks * 32 + g * 8);
                float4 a1 = *(const float4*)(qr + ks * 32 + g * 8 + 4);
                float f[8] = {a0.x, a0.y, a0.z, a0.w, a1.x, a1.y, a1.z, a1.w};
#pragma unroll
                for (int e = 0; e < 8; ++e) {
                    float v = f[e] * scale;
                    unsigned short hi = f2bf(v);
                    qh[mt][ks].u[e] = hi;
                    ql[mt][ks].u[e] = f2bf(v - bf2f(hi));
                }
            }
        }
    }

    f32x4 O[2][8];
#pragma unroll
    for (int mt = 0; mt < 2; ++mt)
#pragma unroll
        for (int nt = 0; nt < 8; ++nt) O[mt][nt] = (f32x4)0.f;
    float m[2][4], l[2][4];
#pragma unroll
    for (int mt = 0; mt < 2; ++mt)
#pragma unroll
        for (int j = 0; j < 4; ++j) { m[mt][j] = -1e30f; l[mt][j] = 0.f; }

    // staging addressing (linear LDS dest; pre-swizzled global source)
    int krow = (lane >> 4) + w * 4;           // +is*16
    int kcbp = (lane & 15) << 4;
    int vrow = (lane >> 3) + w * 8;           // +is*32
    int vcbp = (lane & 7) << 4;
    const unsigned short* kbh = kth + (size_t)(b * NKV_ + kvh) * S_ * HD_;
    const unsigned short* kbl = ktl + (size_t)(b * NKV_ + kvh) * S_ * HD_;
    const unsigned short* vbh = vth + (size_t)(b * NKV_ + kvh) * HD_ * S_;
    const unsigned short* vbl = vtl + (size_t)(b * NKV_ + kvh) * HD_ * S_;

    int kbmax = (q0 + 127) >> 6;
    for (int kb = 0; kb <= kbmax; ++kb) {
        __syncthreads();   // prior tile's K/P/V reads complete
#pragma unroll
        for (int is = 0; is < 4; ++is) {
            int kr = krow + is * 16;
            int ke = (kcbp ^ ((kr & 7) << 4)) >> 1;
            GL16(kbh + (size_t)(kb * 64 + kr) * HD_ + ke, Kh  + is * 4096 + w * 1024);
            GL16(kbl + (size_t)(kb * 64 + kr) * HD_ + ke, Klo + is * 4096 + w * 1024);
            int vr = vrow + is * 32;
            int ve = (vcbp ^ ((vr & 7) << 4)) >> 1;
            GL16(vbh + (size_t)vr * S_ + kb * 64 + ve, Vh  + is * 4096 + w * 1024);
            GL16(vbl + (size_t)vr * S_ + kb * 64 + ve, Vlo + is * 4096 + w * 1024);
        }
        __syncthreads();   // staged data visible (vmcnt drained by barrier)

        bool act = (kb * 64 <= wrowmax);
        f32x4 sc[2][4];
        if (act) {
#pragma unroll
            for (int mt = 0; mt < 2; ++mt)
#pragma unroll
                for (int nt = 0; nt < 4; ++nt) sc[mt][nt] = (f32x4)0.f;
            // QK^T: A=Q frags, B=K rows. K row = 256B; chunk ks -> byte
            // ks*64 + g*16, XOR-unswizzled with the row's staging XOR.
#pragma unroll
            for (int ks = 0; ks < 4; ++ks) {
#pragma unroll
                for (int nt = 0; nt < 4; ++nt) {
                    int r  = nt * 16 + l15;
                    int cb = (ks * 64 + g * 16) ^ ((r & 7) << 4);
                    bf16x8 kf_h = *(const bf16x8*)(Kh  + r * 256 + cb);
                    bf16x8 kf_l = *(const bf16x8*)(Klo + r * 256 + cb);
#pragma unroll
                    for (int mt = 0; mt < 2; ++mt) {
                        sc[mt][nt] = __builtin_amdgcn_mfma_f32_16x16x32_bf16(qh[mt][ks].v, kf_h, sc[mt][nt], 0, 0, 0);
                        sc[mt][nt] = __builtin_amdgcn_mfma_f32_16x16x32_bf16(qh[mt][ks].v, kf_l, sc[mt][nt], 0, 0, 0);
                        sc[mt][nt] = __builtin_amdgcn_mfma_f32_16x16x32_bf16(ql[mt][ks].v, kf_h, sc[mt][nt], 0, 0, 0);
                    }
                }
            }
            // causal mask + online softmax (rows = (lane>>4)*4+j, cols = l15)
#pragma unroll
            for (int mt = 0; mt < 2; ++mt) {
#pragma unroll
                for (int j = 0; j < 4; ++j) {
                    int qrow = wq + mt * 16 + g * 4 + j;
#pragma unroll
                    for (int nt = 0; nt < 4; ++nt) {
                        int col = kb * 64 + nt * 16 + l15;
                        if (col > qrow) sc[mt][nt][j] = -1e30f;
                    }
                    float tmax = fmaxf(fmaxf(sc[mt][0][j], sc[mt][1][j]),
                                       fmaxf(sc[mt][2][j], sc[mt][3][j]));
#pragma unroll
                    for (int off = 8; off; off >>= 1) tmax = fmaxf(tmax, __shfl_xor(tmax, off));
                    float mn = fmaxf(m[mt][j], tmax);
                    float resc = __expf(m[mt][j] - mn);
                    m[mt][j] = mn;
                    float s0 = 0.f;
#pragma unroll
                    for (int nt = 0; nt < 4; ++nt) {
                        float p = __expf(sc[mt][nt][j] - mn);
                        sc[mt][nt][j] = p;
                        s0 += p;
                    }
#pragma unroll
                    for (int off = 8; off; off >>= 1) s0 += __shfl_xor(s0, off);
                    l[mt][j] = l[mt][j] * resc + s0;
#pragma unroll
                    for (int nt = 0; nt < 8; ++nt) O[mt][nt][j] *= resc;
                }
            }
        }
        __syncthreads();   // all waves done reading K LDS before P overlays it

        if (act) {
            // write P (packed hi|lo<<16) into own 8KB slice over Kh/Klo
            char* P = lds + w * 8192;
#pragma unroll
            for (int mt = 0; mt < 2; ++mt)
#pragma unroll
                for (int nt = 0; nt < 4; ++nt)
#pragma unroll
                    for (int j = 0; j < 4; ++j) {
                        int prow = mt * 16 + g * 4 + j;
                        int pcol = nt * 16 + l15;
                        float pv = sc[mt][nt][j];
                        unsigned short ph = f2bf(pv);
                        unsigned short pl = f2bf(pv - bf2f(ph));
                        unsigned pk = (unsigned)ph | ((unsigned)pl << 16);
                        *(unsigned*)(P + prow * 256 + ((pcol * 4) ^ ((prow & 7) << 5))) = pk;
                    }
            // PV: A = P rows (same-wave LDS read-back), B = V^T rows
#pragma unroll
            for (int ks2 = 0; ks2 < 2; ++ks2) {
                U8 pah[2], pal[2];
#pragma unroll
                for (int mt = 0; mt < 2; ++mt) {
                    int arow = mt * 16 + l15;
                    int ab   = arow * 256 + ((ks2 * 128 + g * 32) ^ ((arow & 7) << 5));
                    uint4 p0 = *(const uint4*)(P + ab);
                    uint4 p1 = *(const uint4*)(P + ab + 16);
                    unsigned pw[8] = {p0.x, p0.y, p0.z, p0.w, p1.x, p1.y, p1.z, p1.w};
#pragma unroll
                    for (int e = 0; e < 8; ++e) {
                        pah[mt].u[e] = (unsigned short)(pw[e] & 0xFFFF);
                        pal[mt].u[e] = (unsigned short)(pw[e] >> 16);
                    }
                }
#pragma unroll
                for (int nt = 0; nt < 8; ++nt) {
                    int r  = nt * 16 + l15;
                    int cb = (ks2 * 64 + g * 16) ^ ((r & 7) << 4);
                    bf16x8 vf_h = *(const bf16x8*)(Vh  + r * 128 + cb);
                    bf16x8 vf_l = *(const bf16x8*)(Vlo + r * 128 + cb);
#pragma unroll
                    for (int mt = 0; mt < 2; ++mt) {
                        O[mt][nt] = __builtin_amdgcn_mfma_f32_16x16x32_bf16(pah[mt].v, vf_h, O[mt][nt], 0, 0, 0);
                        O[mt][nt] = __builtin_amdgcn_mfma_f32_16x16x32_bf16(pal[mt].v, vf_h, O[mt][nt], 0, 0, 0);
                        O[mt][nt] = __builtin_amdgcn_mfma_f32_16x16x32_bf16(pah[mt].v, vf_l, O[mt][nt], 0, 0, 0);
                    }
                }
            }
        }
    }

    // epilogue: O / l -> aout
#pragma unroll
    for (int mt = 0; mt < 2; ++mt) {
        float invl[4];
#pragma unroll
        for (int j = 0; j < 4; ++j) invl[j] = 1.f / l[mt][j];
#pragma unroll
        for (int nt = 0; nt < 8; ++nt)
#pragma unroll
            for (int j = 0; j < 4; ++j) {
                int sq  = wq + mt * 16 + g * 4 + j;
                int col = h * 128 + nt * 16 + l15;
                aout[(size_t)(b * S_ + sq) * 4096 + col] = O[mt][nt][j] * invl[j];
            }
    }
}

// ---------------------------------------------------------------------------
// Workspace map (bytes), peak ~237 MB; aliases are stream-order safe:
//  0 cost | 512K sint | 1M Xh | 21.9M Xl | 42.9M WqH | 63.9M WqL |
//  84.9M KVH | 95.4M KVL | 105.9M WoH | 126.8M WoL | 141M qraw | 205M kv
//  qt   -> 1048576..68157440          (X/Wq splits dead after Q GEMM)
//  vtTh -> 68157440, vtTl -> 76546048 (ends 84934656)
//  kth  -> 84934656 (+8388608), ktl -> 93323264 (+8388608, ends 101711872
//          < WoH at 105906176)        (KV weight splits dead after KV GEMM)
//  Ah2  -> 1048576, Al2 -> 34603008   (qt/vtT dead after attn)
// ---------------------------------------------------------------------------
extern "C" void kernel_launch(void* const* d_in, const int* in_sizes, int n_in,
                              void* d_out, int out_size, void* d_ws, size_t ws_size,
                              hipStream_t stream) {
    const float* X   = (const float*)d_in[0];
    const float* Wq  = (const float*)d_in[1];
    const float* Wk  = (const float*)d_in[2];
    const float* Wv  = (const float*)d_in[3];
    const float* Wo  = (const float*)d_in[4];
    const float* qnw = (const float*)d_in[5];
    const float* knw = (const float*)d_in[6];
    const int*   pos = (const int*)d_in[7];
    float* out = (float*)d_out;

    char* ws = (char*)d_ws;
    float*          cost = (float*)(ws + 0);
    float*          sint = (float*)(ws + 524288);
    unsigned short* Xh   = (unsigned short*)(ws + 1048576);
    unsigned short* Xl   = (unsigned short*)(ws + 22020096);
    unsigned short* WqH  = (unsigned short*)(ws + 42991616);
    unsigned short* WqL  = (unsigned short*)(ws + 63963136);
    unsigned short* KVH  = (unsigned short*)(ws + 84934656);
    unsigned short* KVL  = (unsigned short*)(ws + 95420416);
    unsigned short* WoH  = (unsigned short*)(ws + 105906176);
    unsigned short* WoL  = (unsigned short*)(ws + 126877696);
    float*          qraw = (float*)(ws + 147849216);  // [4096][4096]
    float*          kv   = (float*)(ws + 214958080);  // [4096][2048]
    float*          qt   = (float*)(ws + 1048576);    // alias
    unsigned short* vtTh = (unsigned short*)(ws + 68157440);  // alias
    unsigned short* vtTl = (unsigned short*)(ws + 76546048);  // alias
    unsigned short* kth  = (unsigned short*)(ws + 84934656);  // alias
    unsigned short* ktl  = (unsigned short*)(ws + 93323264);  // alias (FIXED: was 93321216, overlapped kth by 2048B)
    unsigned short* Ah2  = (unsigned short*)(ws + 1048576);   // alias
    unsigned short* Al2  = (unsigned short*)(ws + 34603008);  // alias

    rope_table_kernel<<<S_, 64, 0, stream>>>(cost, sint);

    convert_split<<<(4096 * 2560 / 4 + 255) / 256, 256, 0, stream>>>(X, Xh, Xl, 4096 * 2560 / 4);
    convert_T<<<dim3(4096 / 32, 2560 / 32), 256, 0, stream>>>(Wq, WqH, WqL, HID_, 4096);
    convert_T<<<dim3(1024 / 32, 2560 / 32), 256, 0, stream>>>(Wk, KVH, KVL, HID_, 1024);
    convert_T<<<dim3(1024 / 32, 2560 / 32), 256, 0, stream>>>(Wv, KVH + 1024 * 2560, KVL + 1024 * 2560, HID_, 1024);
    convert_T<<<dim3(2560 / 32, 4096 / 32), 256, 0, stream>>>(Wo, WoH, WoL, 4096, 2560);

    gemm_split<<<dim3(4096 / 128, 4096 / 128), 256, 0, stream>>>(Xh, Xl, WqH, WqL, qraw, HID_, 4096);
    gemm_split<<<dim3(2048 / 128, 4096 / 128), 256, 0, stream>>>(Xh, Xl, KVH, KVL, kv, HID_, 2048);

    rmsnorm_rope_kernel<<<(B_ * S_ * NH_) / 4, 256, 0, stream>>>(qraw, qnw, cost, sint, pos, qt, NH_, 4096);
    rmsnorm_rope_k_split<<<(B_ * S_ * NKV_) / 4, 256, 0, stream>>>(kv, knw, cost, sint, pos, kth, ktl);
    vsplitT<<<dim3(64, 4, 16), 256, 0, stream>>>(kv, vtTh, vtTl);

    attn_mfma<<<dim3(16, 32, 2), 256, 0, stream>>>(qt, kth, ktl, vtTh, vtTl, qraw);

    convert_split<<<(4096 * 4096 / 4 + 255) / 256, 256, 0, stream>>>(qraw, Ah2, Al2, 4096 * 4096 / 4);
    gemm_split<<<dim3(2560 / 128, 4096 / 128), 256, 0, stream>>>(Ah2, Al2, WoH, WoL, out, 4096, 2560);
}